// Round 2
// baseline (1741.350 us; speedup 1.0000x reference)
//
#include <hip/hip_runtime.h>

// GCN link classifier, fp32 throughout.
// Pipeline:
//   deg -> dinv
//   agg1 = A_norm @ x            (aggregate 32-dim input FIRST, then W1)
//   h1   = relu(agg1 @ W1 + b1)            [N,128]
//   xl2  = h1 @ W2                          [N,32]  (transform first, then aggregate)
//   agg2 = A_norm @ xl2
//   h2   = relu(agg2 + b2)   (folded into k_h2g)
//   g_top = h2 @ Wm1[:32], g_bot = h2 @ Wm1[32:]    (edge-MLP factorization)
//   out[e] = relu(g_top[u] + g_bot[v] + bm1) @ Wm2 + bm2

#define HIDN 32

__global__ void k_deg(const int* __restrict__ dst, int E, int* __restrict__ deg) {
    int e = blockIdx.x * blockDim.x + threadIdx.x;
    if (e < E) atomicAdd(&deg[dst[e]], 1);
}

__global__ void k_dinv(const int* __restrict__ deg, int N, float* __restrict__ dinv) {
    int i = blockIdx.x * blockDim.x + threadIdx.x;
    if (i < N) dinv[i] = rsqrtf((float)(deg[i] + 1));   // +1 = self loop
}

// agg[i] = dinv[i]^2 * v[i]   (self-loop term, full overwrite => no zeroing needed)
__global__ void k_selfinit(const float4* __restrict__ v, const float* __restrict__ dinv,
                           int N, float4* __restrict__ agg) {
    int t = blockIdx.x * blockDim.x + threadIdx.x;   // N*8 threads (float4 quads)
    if (t >= N * 8) return;
    int i = t >> 3;
    float w = dinv[i]; w *= w;
    float4 a = v[t];
    a.x *= w; a.y *= w; a.z *= w; a.w *= w;
    agg[t] = a;
}

// agg[dst] += dinv[src]*dinv[dst] * v[src]   (8 threads/edge, float4 each)
__global__ void k_scatter(const int* __restrict__ src, const int* __restrict__ dst, int E,
                          const float4* __restrict__ v, const float* __restrict__ dinv,
                          float* __restrict__ agg) {
    int t = blockIdx.x * blockDim.x + threadIdx.x;   // E*8 threads
    if (t >= E * 8) return;
    int e = t >> 3, q = t & 7;
    int s = src[e], d = dst[e];
    float w = dinv[s] * dinv[d];
    float4 xs = v[(size_t)s * 8 + q];
    float* base = agg + (size_t)d * 32 + q * 4;
    atomicAdd(base + 0, w * xs.x);
    atomicAdd(base + 1, w * xs.y);
    atomicAdd(base + 2, w * xs.z);
    atomicAdd(base + 3, w * xs.w);
}

// h1 = relu(agg1 @ W1 + b1)   thread per (i,j), j in [0,128)
__global__ void k_lin1(const float* __restrict__ agg, const float* __restrict__ W1,
                       const float* __restrict__ b1, int N, float* __restrict__ h1) {
    int t = blockIdx.x * blockDim.x + threadIdx.x;   // N*128
    if (t >= N * 128) return;
    int i = t >> 7, j = t & 127;
    const float* a = agg + (size_t)i * 32;
    float s = b1[j];
#pragma unroll
    for (int k = 0; k < 32; ++k) s = fmaf(a[k], W1[k * 128 + j], s);
    h1[t] = fmaxf(s, 0.f);
}

// xl2 = h1 @ W2   thread per (i,j), j in [0,32)
__global__ void k_lin2(const float* __restrict__ h1, const float* __restrict__ W2,
                       int N, float* __restrict__ xl2) {
    int t = blockIdx.x * blockDim.x + threadIdx.x;   // N*32
    if (t >= N * 32) return;
    int i = t >> 5, j = t & 31;
    const float* hrow = h1 + (size_t)i * 128;
    float s = 0.f;
#pragma unroll 8
    for (int k = 0; k < 128; ++k) s = fmaf(hrow[k], W2[k * 32 + j], s);
    xl2[t] = s;
}

// h2 = relu(agg2 + b2); g_top = h2 @ Wm1[0:32,:], g_bot = h2 @ Wm1[32:64,:]
__global__ void k_h2g(const float* __restrict__ agg2, const float* __restrict__ b2,
                      const float* __restrict__ Wm1, int N,
                      float* __restrict__ gt, float* __restrict__ gb) {
    __shared__ float ash[8][33];
    int li = threadIdx.x >> 5, j = threadIdx.x & 31;
    int i = blockIdx.x * 8 + li;
    if (i < N) ash[li][j] = fmaxf(agg2[(size_t)i * 32 + j] + b2[j], 0.f);
    __syncthreads();
    if (i >= N) return;
    float st = 0.f, sb = 0.f;
#pragma unroll
    for (int k = 0; k < 32; ++k) {
        float a = ash[li][k];
        st = fmaf(a, Wm1[k * 32 + j], st);
        sb = fmaf(a, Wm1[(k + 32) * 32 + j], sb);
    }
    gt[(size_t)i * 32 + j] = st;
    gb[(size_t)i * 32 + j] = sb;
}

// out[e] = relu(g_top[u] + g_bot[v] + bm1) @ Wm2 + bm2
__global__ void k_edge(const int* __restrict__ ps, const int* __restrict__ pd, int Ep,
                       const int* __restrict__ ns, const int* __restrict__ nd, int En,
                       const float4* __restrict__ gt4, const float4* __restrict__ gb4,
                       const float* __restrict__ bm1, const float* __restrict__ Wm2,
                       const float* __restrict__ bm2, float2* __restrict__ out) {
    int e = blockIdx.x * blockDim.x + threadIdx.x;
    int E = Ep + En;
    if (e >= E) return;
    int u, v;
    if (e < Ep) { u = ps[e]; v = pd[e]; }
    else        { u = ns[e - Ep]; v = nd[e - Ep]; }
    float o0 = bm2[0], o1 = bm2[1];
#pragma unroll
    for (int q = 0; q < 8; ++q) {
        float4 a = gt4[(size_t)u * 8 + q];
        float4 b = gb4[(size_t)v * 8 + q];
        float h;
        h = fmaxf(a.x + b.x + bm1[q * 4 + 0], 0.f);
        o0 = fmaf(h, Wm2[(q * 4 + 0) * 2 + 0], o0); o1 = fmaf(h, Wm2[(q * 4 + 0) * 2 + 1], o1);
        h = fmaxf(a.y + b.y + bm1[q * 4 + 1], 0.f);
        o0 = fmaf(h, Wm2[(q * 4 + 1) * 2 + 0], o0); o1 = fmaf(h, Wm2[(q * 4 + 1) * 2 + 1], o1);
        h = fmaxf(a.z + b.z + bm1[q * 4 + 2], 0.f);
        o0 = fmaf(h, Wm2[(q * 4 + 2) * 2 + 0], o0); o1 = fmaf(h, Wm2[(q * 4 + 2) * 2 + 1], o1);
        h = fmaxf(a.w + b.w + bm1[q * 4 + 3], 0.f);
        o0 = fmaf(h, Wm2[(q * 4 + 3) * 2 + 0], o0); o1 = fmaf(h, Wm2[(q * 4 + 3) * 2 + 1], o1);
    }
    out[e] = make_float2(o0, o1);
}

extern "C" void kernel_launch(void* const* d_in, const int* in_sizes, int n_in,
                              void* d_out, int out_size, void* d_ws, size_t ws_size,
                              hipStream_t stream) {
    const float* x   = (const float*)d_in[0];
    const int*   pei = (const int*)d_in[1];
    const int*   nei = (const int*)d_in[2];
    const float* W1  = (const float*)d_in[3];
    const float* b1  = (const float*)d_in[4];
    const float* W2  = (const float*)d_in[5];
    const float* b2  = (const float*)d_in[6];
    const float* Wm1 = (const float*)d_in[7];
    const float* bm1 = (const float*)d_in[8];
    const float* Wm2 = (const float*)d_in[9];
    const float* bm2 = (const float*)d_in[10];

    const int N  = in_sizes[0] / HIDN;
    const int Ep = in_sizes[1] / 2;
    const int En = in_sizes[2] / 2;
    const int* ps = pei;            // pos src
    const int* pd = pei + Ep;       // pos dst
    const int* ns = nei;
    const int* nd = nei + En;

    // workspace layout (256B-aligned slabs)
    char* ws = (char*)d_ws;
    size_t off = 0;
    auto alloc = [&](size_t bytes) { size_t o = off; off += (bytes + 255) & ~(size_t)255; return o; };
    int*   deg  = (int*)(ws + alloc((size_t)N * 4));
    float* dinv = (float*)(ws + alloc((size_t)N * 4));
    float* agg1 = (float*)(ws + alloc((size_t)N * HIDN * 4));
    float* xl2  = (float*)(ws + alloc((size_t)N * HIDN * 4));
    float* agg2 = (float*)(ws + alloc((size_t)N * HIDN * 4));
    float* h1   = (float*)(ws + alloc((size_t)N * 128 * 4));
    // g_top/g_bot reuse h1's slab (h1 is dead once xl2 is computed)
    float* gt = h1;
    float* gb = h1 + (size_t)N * HIDN;

    hipMemsetAsync(deg, 0, (size_t)N * 4, stream);
    k_deg<<<(Ep + 255) / 256, 256, 0, stream>>>(pd, Ep, deg);
    k_dinv<<<(N + 255) / 256, 256, 0, stream>>>(deg, N, dinv);

    // layer 1: aggregate x (32-dim), then W1
    k_selfinit<<<(N * 8 + 255) / 256, 256, 0, stream>>>((const float4*)x, dinv, N, (float4*)agg1);
    k_scatter<<<(int)(((size_t)Ep * 8 + 255) / 256), 256, 0, stream>>>(ps, pd, Ep, (const float4*)x, dinv, agg1);
    k_lin1<<<(int)(((size_t)N * 128 + 255) / 256), 256, 0, stream>>>(agg1, W1, b1, N, h1);

    // layer 2: transform (128->32) first, then aggregate
    k_lin2<<<(int)(((size_t)N * 32 + 255) / 256), 256, 0, stream>>>(h1, W2, N, xl2);
    k_selfinit<<<(N * 8 + 255) / 256, 256, 0, stream>>>((const float4*)xl2, dinv, N, (float4*)agg2);
    k_scatter<<<(int)(((size_t)Ep * 8 + 255) / 256), 256, 0, stream>>>(ps, pd, Ep, (const float4*)xl2, dinv, agg2);

    // h2 = relu(agg2+b2); factor edge MLP through nodes
    k_h2g<<<(N + 7) / 8, 256, 0, stream>>>(agg2, b2, Wm1, N, gt, gb);

    // edge MLP over pos+neg edges
    k_edge<<<(Ep + En + 255) / 256, 256, 0, stream>>>(ps, pd, Ep, ns, nd, En,
                                                      (const float4*)gt, (const float4*)gb,
                                                      bm1, Wm2, bm2, (float2*)d_out);
}

// Round 3
// 639.917 us; speedup vs baseline: 2.7212x; 2.7212x over previous
//
#include <hip/hip_runtime.h>

// GCN link classifier, fp32, CSR-gather aggregation (no fp32 atomics).
// Pipeline:
//   deg -> rowptr (scan) -> csr fill          (graph built once, reused twice)
//   agg1 = A_norm @ x        via gather
//   h1   = relu(agg1 @ W1 + b1)      [N,128]
//   xl2  = h1 @ W2                    [N,32]
//   agg2 = A_norm @ xl2      via gather
//   g_top = relu(agg2+b2) @ Wm1[:32], g_bot = .. @ Wm1[32:]
//   out[e] = relu(g_top[u] + g_bot[v] + bm1) @ Wm2 + bm2

#define HIDN 32
#define SCAN_B 256

__global__ void k_deg(const int* __restrict__ dst, int E, int* __restrict__ deg) {
    int e = blockIdx.x * blockDim.x + threadIdx.x;
    if (e < E) atomicAdd(&deg[dst[e]], 1);
}

__global__ void k_dinv(const int* __restrict__ deg, int N, float* __restrict__ dinv) {
    int i = blockIdx.x * blockDim.x + threadIdx.x;
    if (i < N) dinv[i] = rsqrtf((float)(deg[i] + 1));   // +1 = self loop
}

// per-block exclusive scan; bsum[b] = block total
__global__ void k_scan1(const int* __restrict__ deg, int N,
                        int* __restrict__ part, int* __restrict__ bsum) {
    __shared__ int sh[SCAN_B];
    int t = threadIdx.x, i = blockIdx.x * SCAN_B + t;
    int v = (i < N) ? deg[i] : 0;
    sh[t] = v; __syncthreads();
    for (int o = 1; o < SCAN_B; o <<= 1) {
        int a = (t >= o) ? sh[t - o] : 0;
        __syncthreads();
        sh[t] += a;
        __syncthreads();
    }
    if (i < N) part[i] = sh[t] - v;          // exclusive
    if (t == SCAN_B - 1) bsum[blockIdx.x] = sh[t];
}

// single-block exclusive scan of block sums (nb <= 1024)
__global__ void k_scan2(int* __restrict__ bsum, int nb) {
    __shared__ int sh[1024];
    int t = threadIdx.x;
    int v = (t < nb) ? bsum[t] : 0;
    sh[t] = v; __syncthreads();
    for (int o = 1; o < 1024; o <<= 1) {
        int a = (t >= o) ? sh[t - o] : 0;
        __syncthreads();
        sh[t] += a;
        __syncthreads();
    }
    if (t < nb) bsum[t] = sh[t] - v;         // exclusive, in place
}

// rowptr[i] = part[i] + bsum[i/SCAN_B]; cursor = rowptr; rowptr[N] = E
__global__ void k_scan3(const int* __restrict__ part, const int* __restrict__ bsum,
                        int N, int E, int* __restrict__ rowptr, int* __restrict__ cursor) {
    int i = blockIdx.x * blockDim.x + threadIdx.x;
    if (i < N) {
        int r = part[i] + bsum[i / SCAN_B];
        rowptr[i] = r;
        cursor[i] = r;
    }
    if (i == N) rowptr[N] = E;
}

__global__ void k_fill(const int* __restrict__ src, const int* __restrict__ dst, int E,
                       int* __restrict__ cursor, int* __restrict__ csr) {
    int e = blockIdx.x * blockDim.x + threadIdx.x;
    if (e < E) {
        int j = atomicAdd(&cursor[dst[e]], 1);
        csr[j] = src[e];
    }
}

// agg[i] = dinv[i] * ( dinv[i]*v[i] + sum_{s in inlist(i)} dinv[s]*v[s] )
// 8 threads per node, one float4 lane-quad each.
__global__ void k_gather(const float4* __restrict__ v, const float* __restrict__ dinv,
                         const int* __restrict__ rowptr, const int* __restrict__ csr,
                         int N, float4* __restrict__ agg) {
    int t = blockIdx.x * blockDim.x + threadIdx.x;   // N*8
    if (t >= N * 8) return;
    int i = t >> 3, q = t & 7;
    float di = dinv[i];
    float4 a = v[(size_t)i * 8 + q];
    float4 acc = make_float4(di * a.x, di * a.y, di * a.z, di * a.w);
    int beg = rowptr[i], end = rowptr[i + 1];
    for (int j = beg; j < end; ++j) {
        int s = csr[j];
        float w = dinv[s];
        float4 xs = v[(size_t)s * 8 + q];
        acc.x = fmaf(w, xs.x, acc.x);
        acc.y = fmaf(w, xs.y, acc.y);
        acc.z = fmaf(w, xs.z, acc.z);
        acc.w = fmaf(w, xs.w, acc.w);
    }
    acc.x *= di; acc.y *= di; acc.z *= di; acc.w *= di;
    agg[t] = acc;
}

// h1 = relu(agg1 @ W1 + b1)   thread per (i,j), j in [0,128)
__global__ void k_lin1(const float* __restrict__ agg, const float* __restrict__ W1,
                       const float* __restrict__ b1, int N, float* __restrict__ h1) {
    int t = blockIdx.x * blockDim.x + threadIdx.x;   // N*128
    if (t >= N * 128) return;
    int i = t >> 7, j = t & 127;
    const float* a = agg + (size_t)i * 32;
    float s = b1[j];
#pragma unroll
    for (int k = 0; k < 32; ++k) s = fmaf(a[k], W1[k * 128 + j], s);
    h1[t] = fmaxf(s, 0.f);
}

// xl2 = h1 @ W2   thread per (i,j), j in [0,32)
__global__ void k_lin2(const float* __restrict__ h1, const float* __restrict__ W2,
                       int N, float* __restrict__ xl2) {
    int t = blockIdx.x * blockDim.x + threadIdx.x;   // N*32
    if (t >= N * 32) return;
    int i = t >> 5, j = t & 31;
    const float* hrow = h1 + (size_t)i * 128;
    float s = 0.f;
#pragma unroll 8
    for (int k = 0; k < 128; ++k) s = fmaf(hrow[k], W2[k * 32 + j], s);
    xl2[t] = s;
}

// h2 = relu(agg2 + b2); g_top = h2 @ Wm1[0:32,:], g_bot = h2 @ Wm1[32:64,:]
__global__ void k_h2g(const float* __restrict__ agg2, const float* __restrict__ b2,
                      const float* __restrict__ Wm1, int N,
                      float* __restrict__ gt, float* __restrict__ gb) {
    __shared__ float ash[8][33];
    int li = threadIdx.x >> 5, j = threadIdx.x & 31;
    int i = blockIdx.x * 8 + li;
    if (i < N) ash[li][j] = fmaxf(agg2[(size_t)i * 32 + j] + b2[j], 0.f);
    __syncthreads();
    if (i >= N) return;
    float st = 0.f, sb = 0.f;
#pragma unroll
    for (int k = 0; k < 32; ++k) {
        float a = ash[li][k];
        st = fmaf(a, Wm1[k * 32 + j], st);
        sb = fmaf(a, Wm1[(k + 32) * 32 + j], sb);
    }
    gt[(size_t)i * 32 + j] = st;
    gb[(size_t)i * 32 + j] = sb;
}

// out[e] = relu(g_top[u] + g_bot[v] + bm1) @ Wm2 + bm2
__global__ void k_edge(const int* __restrict__ ps, const int* __restrict__ pd, int Ep,
                       const int* __restrict__ ns, const int* __restrict__ nd, int En,
                       const float4* __restrict__ gt4, const float4* __restrict__ gb4,
                       const float* __restrict__ bm1, const float* __restrict__ Wm2,
                       const float* __restrict__ bm2, float2* __restrict__ out) {
    int e = blockIdx.x * blockDim.x + threadIdx.x;
    int E = Ep + En;
    if (e >= E) return;
    int u, v;
    if (e < Ep) { u = ps[e]; v = pd[e]; }
    else        { u = ns[e - Ep]; v = nd[e - Ep]; }
    float o0 = bm2[0], o1 = bm2[1];
#pragma unroll
    for (int q = 0; q < 8; ++q) {
        float4 a = gt4[(size_t)u * 8 + q];
        float4 b = gb4[(size_t)v * 8 + q];
        float h;
        h = fmaxf(a.x + b.x + bm1[q * 4 + 0], 0.f);
        o0 = fmaf(h, Wm2[(q * 4 + 0) * 2 + 0], o0); o1 = fmaf(h, Wm2[(q * 4 + 0) * 2 + 1], o1);
        h = fmaxf(a.y + b.y + bm1[q * 4 + 1], 0.f);
        o0 = fmaf(h, Wm2[(q * 4 + 1) * 2 + 0], o0); o1 = fmaf(h, Wm2[(q * 4 + 1) * 2 + 1], o1);
        h = fmaxf(a.z + b.z + bm1[q * 4 + 2], 0.f);
        o0 = fmaf(h, Wm2[(q * 4 + 2) * 2 + 0], o0); o1 = fmaf(h, Wm2[(q * 4 + 2) * 2 + 1], o1);
        h = fmaxf(a.w + b.w + bm1[q * 4 + 3], 0.f);
        o0 = fmaf(h, Wm2[(q * 4 + 3) * 2 + 0], o0); o1 = fmaf(h, Wm2[(q * 4 + 3) * 2 + 1], o1);
    }
    out[e] = make_float2(o0, o1);
}

extern "C" void kernel_launch(void* const* d_in, const int* in_sizes, int n_in,
                              void* d_out, int out_size, void* d_ws, size_t ws_size,
                              hipStream_t stream) {
    const float* x   = (const float*)d_in[0];
    const int*   pei = (const int*)d_in[1];
    const int*   nei = (const int*)d_in[2];
    const float* W1  = (const float*)d_in[3];
    const float* b1  = (const float*)d_in[4];
    const float* W2  = (const float*)d_in[5];
    const float* b2  = (const float*)d_in[6];
    const float* Wm1 = (const float*)d_in[7];
    const float* bm1 = (const float*)d_in[8];
    const float* Wm2 = (const float*)d_in[9];
    const float* bm2 = (const float*)d_in[10];

    const int N  = in_sizes[0] / HIDN;
    const int Ep = in_sizes[1] / 2;
    const int En = in_sizes[2] / 2;
    const int* ps = pei;            // pos src
    const int* pd = pei + Ep;       // pos dst
    const int* ns = nei;
    const int* nd = nei + En;
    const int nb = (N + SCAN_B - 1) / SCAN_B;   // scan blocks (must be <= 1024)

    // workspace layout (256B-aligned slabs)
    char* ws = (char*)d_ws;
    size_t off = 0;
    auto alloc = [&](size_t bytes) { size_t o = off; off += (bytes + 255) & ~(size_t)255; return o; };
    int*   deg    = (int*)(ws + alloc((size_t)N * 4));
    float* dinv   = (float*)(ws + alloc((size_t)N * 4));
    int*   part   = (int*)(ws + alloc((size_t)N * 4));
    int*   bsum   = (int*)(ws + alloc((size_t)1024 * 4));
    int*   rowptr = (int*)(ws + alloc((size_t)(N + 1) * 4));
    int*   cursor = (int*)(ws + alloc((size_t)N * 4));
    int*   csr    = (int*)(ws + alloc((size_t)Ep * 4));
    float* agg1   = (float*)(ws + alloc((size_t)N * HIDN * 4));
    float* xl2    = (float*)(ws + alloc((size_t)N * HIDN * 4));
    float* agg2   = (float*)(ws + alloc((size_t)N * HIDN * 4));
    float* h1     = (float*)(ws + alloc((size_t)N * 128 * 4));
    // g_top/g_bot reuse h1's slab (h1 dead once xl2 computed)
    float* gt = h1;
    float* gb = h1 + (size_t)N * HIDN;

    // ---- CSR build (once; reused by both layers) ----
    hipMemsetAsync(deg, 0, (size_t)N * 4, stream);
    k_deg<<<(Ep + 255) / 256, 256, 0, stream>>>(pd, Ep, deg);
    k_dinv<<<(N + 255) / 256, 256, 0, stream>>>(deg, N, dinv);
    k_scan1<<<nb, SCAN_B, 0, stream>>>(deg, N, part, bsum);
    k_scan2<<<1, 1024, 0, stream>>>(bsum, nb);
    k_scan3<<<(N + 256) / 256, 256, 0, stream>>>(part, bsum, N, Ep, rowptr, cursor);
    k_fill<<<(Ep + 255) / 256, 256, 0, stream>>>(ps, pd, Ep, cursor, csr);

    // ---- layer 1: aggregate x (32-dim), then W1 ----
    k_gather<<<(N * 8 + 255) / 256, 256, 0, stream>>>((const float4*)x, dinv, rowptr, csr, N, (float4*)agg1);
    k_lin1<<<(int)(((size_t)N * 128 + 255) / 256), 256, 0, stream>>>(agg1, W1, b1, N, h1);

    // ---- layer 2: transform (128->32) first, then aggregate ----
    k_lin2<<<(int)(((size_t)N * 32 + 255) / 256), 256, 0, stream>>>(h1, W2, N, xl2);
    k_gather<<<(N * 8 + 255) / 256, 256, 0, stream>>>((const float4*)xl2, dinv, rowptr, csr, N, (float4*)agg2);

    // ---- edge-MLP factorization through nodes ----
    k_h2g<<<(N + 7) / 8, 256, 0, stream>>>(agg2, b2, Wm1, N, gt, gb);

    // ---- edge MLP over pos+neg edges ----
    k_edge<<<(Ep + En + 255) / 256, 256, 0, stream>>>(ps, pd, Ep, ns, nd, En,
                                                      (const float4*)gt, (const float4*)gb,
                                                      bm1, Wm2, bm2, (float2*)d_out);
}

// Round 4
// 622.094 us; speedup vs baseline: 2.7992x; 1.0287x over previous
//
#include <hip/hip_runtime.h>

// GCN link classifier, fp32, CSR-gather aggregation, fused layers.
// Pipeline (9 dispatches):
//   memset deg; k_deg; k_scan1(+dinv); k_scan2; k_scan3; k_fill   (CSR build)
//   k_l1: agg1=A@x, h1=relu(agg1@W1+b1), xl2=h1@W2      (fused, per-node)
//   k_l2: agg2=A@xl2, h2=relu(agg2+b2), gt=h2@Wm1[:32], gb=h2@Wm1[32:]
//   k_edge: out[e] = relu(gt[u]+gb[v]+bm1)@Wm2 + bm2

#define HIDN 32
#define SCAN_B 256

__global__ void k_deg(const int* __restrict__ dst, int E, int* __restrict__ deg) {
    int e = blockIdx.x * blockDim.x + threadIdx.x;
    if (e < E) atomicAdd(&deg[dst[e]], 1);
}

// per-block exclusive scan; bsum[b] = block total; also dinv = rsqrt(deg+1)
__global__ void k_scan1(const int* __restrict__ deg, int N,
                        int* __restrict__ part, int* __restrict__ bsum,
                        float* __restrict__ dinv) {
    __shared__ int sh[SCAN_B];
    int t = threadIdx.x, i = blockIdx.x * SCAN_B + t;
    int v = (i < N) ? deg[i] : 0;
    if (i < N) dinv[i] = rsqrtf((float)(v + 1));   // +1 = self loop
    sh[t] = v; __syncthreads();
    for (int o = 1; o < SCAN_B; o <<= 1) {
        int a = (t >= o) ? sh[t - o] : 0;
        __syncthreads();
        sh[t] += a;
        __syncthreads();
    }
    if (i < N) part[i] = sh[t] - v;          // exclusive
    if (t == SCAN_B - 1) bsum[blockIdx.x] = sh[t];
}

// single-block exclusive scan of block sums (nb <= 1024)
__global__ void k_scan2(int* __restrict__ bsum, int nb) {
    __shared__ int sh[1024];
    int t = threadIdx.x;
    int v = (t < nb) ? bsum[t] : 0;
    sh[t] = v; __syncthreads();
    for (int o = 1; o < 1024; o <<= 1) {
        int a = (t >= o) ? sh[t - o] : 0;
        __syncthreads();
        sh[t] += a;
        __syncthreads();
    }
    if (t < nb) bsum[t] = sh[t] - v;         // exclusive, in place
}

// rowptr[i] = part[i] + bsum[i/SCAN_B]; cursor = rowptr; rowptr[N] = E
__global__ void k_scan3(const int* __restrict__ part, const int* __restrict__ bsum,
                        int N, int E, int* __restrict__ rowptr, int* __restrict__ cursor) {
    int i = blockIdx.x * blockDim.x + threadIdx.x;
    if (i < N) {
        int r = part[i] + bsum[i / SCAN_B];
        rowptr[i] = r;
        cursor[i] = r;
    }
    if (i == N) rowptr[N] = E;
}

__global__ void k_fill(const int* __restrict__ src, const int* __restrict__ dst, int E,
                       int* __restrict__ cursor, int* __restrict__ csr) {
    int e = blockIdx.x * blockDim.x + threadIdx.x;
    if (e < E) {
        int j = atomicAdd(&cursor[dst[e]], 1);
        csr[j] = src[e];
    }
}

// ---- fused layer 1: agg1 = A_norm@x (gather); h1 = relu(agg1@W1+b1); xl2 = h1@W2
// block = 256 threads = 8 nodes x 32 lanes (lane j = feature j)
__global__ __launch_bounds__(256) void k_l1(
        const float* __restrict__ x, const float* __restrict__ dinv,
        const int* __restrict__ rowptr, const int* __restrict__ csr,
        const float* __restrict__ W1, const float* __restrict__ b1,
        const float* __restrict__ W2, int N, float* __restrict__ xl2) {
    __shared__ float ash[8][33];
    __shared__ float hsh[8][129];
    int j = threadIdx.x & 31, ln = threadIdx.x >> 5;
    int i = blockIdx.x * 8 + ln;
    float acc = 0.f, di = 0.f;
    int beg = 0, end = 0;
    if (i < N) {
        di = dinv[i];
        acc = di * x[(size_t)i * 32 + j];
        beg = rowptr[i]; end = rowptr[i + 1];
    }
    for (int p = beg; p < end; ++p) {
        int s = csr[p];
        acc = fmaf(dinv[s], x[(size_t)s * 32 + j], acc);   // lanes 0..31 -> 128B coalesced
    }
    ash[ln][j] = acc * di;
    __syncthreads();
    if (i < N) {
        float h0 = b1[j], h1v = b1[j + 32], h2v = b1[j + 64], h3v = b1[j + 96];
#pragma unroll
        for (int k = 0; k < 32; ++k) {
            float a = ash[ln][k];                 // broadcast
            h0  = fmaf(a, W1[k * 128 + j     ], h0);
            h1v = fmaf(a, W1[k * 128 + j + 32], h1v);
            h2v = fmaf(a, W1[k * 128 + j + 64], h2v);
            h3v = fmaf(a, W1[k * 128 + j + 96], h3v);
        }
        hsh[ln][j]      = fmaxf(h0, 0.f);
        hsh[ln][j + 32] = fmaxf(h1v, 0.f);
        hsh[ln][j + 64] = fmaxf(h2v, 0.f);
        hsh[ln][j + 96] = fmaxf(h3v, 0.f);
    }
    __syncthreads();
    if (i >= N) return;
    float s2 = 0.f;
#pragma unroll 16
    for (int k = 0; k < 128; ++k) s2 = fmaf(hsh[ln][k], W2[k * 32 + j], s2);
    xl2[(size_t)i * 32 + j] = s2;
}

// ---- fused layer 2 + edge-MLP factorization:
// agg2 = A_norm@xl2; h2 = relu(agg2+b2); gt = h2@Wm1[:32]; gb = h2@Wm1[32:]
__global__ __launch_bounds__(256) void k_l2(
        const float* __restrict__ xl2, const float* __restrict__ dinv,
        const int* __restrict__ rowptr, const int* __restrict__ csr,
        const float* __restrict__ b2, const float* __restrict__ Wm1,
        int N, float* __restrict__ gt, float* __restrict__ gb) {
    __shared__ float hsh[8][33];
    int j = threadIdx.x & 31, ln = threadIdx.x >> 5;
    int i = blockIdx.x * 8 + ln;
    float acc = 0.f, di = 0.f;
    int beg = 0, end = 0;
    if (i < N) {
        di = dinv[i];
        acc = di * xl2[(size_t)i * 32 + j];
        beg = rowptr[i]; end = rowptr[i + 1];
    }
    for (int p = beg; p < end; ++p) {
        int s = csr[p];
        acc = fmaf(dinv[s], xl2[(size_t)s * 32 + j], acc);
    }
    float h2 = (i < N) ? fmaxf(acc * di + b2[j], 0.f) : 0.f;
    hsh[ln][j] = h2;
    __syncthreads();
    if (i >= N) return;
    float st = 0.f, sb = 0.f;
#pragma unroll
    for (int k = 0; k < 32; ++k) {
        float a = hsh[ln][k];
        st = fmaf(a, Wm1[k * 32 + j], st);
        sb = fmaf(a, Wm1[(k + 32) * 32 + j], sb);
    }
    gt[(size_t)i * 32 + j] = st;
    gb[(size_t)i * 32 + j] = sb;
}

// out[e] = relu(gt[u] + gb[v] + bm1) @ Wm2 + bm2
__global__ void k_edge(const int* __restrict__ ps, const int* __restrict__ pd, int Ep,
                       const int* __restrict__ ns, const int* __restrict__ nd, int En,
                       const float4* __restrict__ gt4, const float4* __restrict__ gb4,
                       const float* __restrict__ bm1, const float* __restrict__ Wm2,
                       const float* __restrict__ bm2, float2* __restrict__ out) {
    int e = blockIdx.x * blockDim.x + threadIdx.x;
    int E = Ep + En;
    if (e >= E) return;
    int u, v;
    if (e < Ep) { u = ps[e]; v = pd[e]; }
    else        { u = ns[e - Ep]; v = nd[e - Ep]; }
    float o0 = bm2[0], o1 = bm2[1];
#pragma unroll
    for (int q = 0; q < 8; ++q) {
        float4 a = gt4[(size_t)u * 8 + q];
        float4 b = gb4[(size_t)v * 8 + q];
        float h;
        h = fmaxf(a.x + b.x + bm1[q * 4 + 0], 0.f);
        o0 = fmaf(h, Wm2[(q * 4 + 0) * 2 + 0], o0); o1 = fmaf(h, Wm2[(q * 4 + 0) * 2 + 1], o1);
        h = fmaxf(a.y + b.y + bm1[q * 4 + 1], 0.f);
        o0 = fmaf(h, Wm2[(q * 4 + 1) * 2 + 0], o0); o1 = fmaf(h, Wm2[(q * 4 + 1) * 2 + 1], o1);
        h = fmaxf(a.z + b.z + bm1[q * 4 + 2], 0.f);
        o0 = fmaf(h, Wm2[(q * 4 + 2) * 2 + 0], o0); o1 = fmaf(h, Wm2[(q * 4 + 2) * 2 + 1], o1);
        h = fmaxf(a.w + b.w + bm1[q * 4 + 3], 0.f);
        o0 = fmaf(h, Wm2[(q * 4 + 3) * 2 + 0], o0); o1 = fmaf(h, Wm2[(q * 4 + 3) * 2 + 1], o1);
    }
    out[e] = make_float2(o0, o1);
}

extern "C" void kernel_launch(void* const* d_in, const int* in_sizes, int n_in,
                              void* d_out, int out_size, void* d_ws, size_t ws_size,
                              hipStream_t stream) {
    const float* x   = (const float*)d_in[0];
    const int*   pei = (const int*)d_in[1];
    const int*   nei = (const int*)d_in[2];
    const float* W1  = (const float*)d_in[3];
    const float* b1  = (const float*)d_in[4];
    const float* W2  = (const float*)d_in[5];
    const float* b2  = (const float*)d_in[6];
    const float* Wm1 = (const float*)d_in[7];
    const float* bm1 = (const float*)d_in[8];
    const float* Wm2 = (const float*)d_in[9];
    const float* bm2 = (const float*)d_in[10];

    const int N  = in_sizes[0] / HIDN;
    const int Ep = in_sizes[1] / 2;
    const int En = in_sizes[2] / 2;
    const int* ps = pei;            // pos src
    const int* pd = pei + Ep;       // pos dst
    const int* ns = nei;
    const int* nd = nei + En;
    const int nb = (N + SCAN_B - 1) / SCAN_B;   // scan blocks (<= 1024)

    // workspace layout (256B-aligned slabs)
    char* ws = (char*)d_ws;
    size_t off = 0;
    auto alloc = [&](size_t bytes) { size_t o = off; off += (bytes + 255) & ~(size_t)255; return o; };
    int*   deg    = (int*)(ws + alloc((size_t)N * 4));
    float* dinv   = (float*)(ws + alloc((size_t)N * 4));
    int*   part   = (int*)(ws + alloc((size_t)N * 4));
    int*   bsum   = (int*)(ws + alloc((size_t)1024 * 4));
    int*   rowptr = (int*)(ws + alloc((size_t)(N + 1) * 4));
    int*   cursor = (int*)(ws + alloc((size_t)N * 4));
    int*   csr    = (int*)(ws + alloc((size_t)Ep * 4));
    float* xl2    = (float*)(ws + alloc((size_t)N * HIDN * 4));
    float* gt     = (float*)(ws + alloc((size_t)N * HIDN * 4));
    float* gb     = (float*)(ws + alloc((size_t)N * HIDN * 4));

    // ---- CSR build (once; reused by both layers) ----
    hipMemsetAsync(deg, 0, (size_t)N * 4, stream);
    k_deg<<<(Ep + 255) / 256, 256, 0, stream>>>(pd, Ep, deg);
    k_scan1<<<nb, SCAN_B, 0, stream>>>(deg, N, part, bsum, dinv);
    k_scan2<<<1, 1024, 0, stream>>>(bsum, nb);
    k_scan3<<<(N + 256) / 256, 256, 0, stream>>>(part, bsum, N, Ep, rowptr, cursor);
    k_fill<<<(Ep + 255) / 256, 256, 0, stream>>>(ps, pd, Ep, cursor, csr);

    // ---- fused GCN layers ----
    k_l1<<<(N + 7) / 8, 256, 0, stream>>>(x, dinv, rowptr, csr, W1, b1, W2, N, xl2);
    k_l2<<<(N + 7) / 8, 256, 0, stream>>>(xl2, dinv, rowptr, csr, b2, Wm1, N, gt, gb);

    // ---- edge MLP over pos+neg edges ----
    k_edge<<<(Ep + En + 255) / 256, 256, 0, stream>>>(ps, pd, Ep, ns, nd, En,
                                                      (const float4*)gt, (const float4*)gb,
                                                      bm1, Wm2, bm2, (float2*)d_out);
}

// Round 5
// 534.838 us; speedup vs baseline: 3.2558x; 1.1631x over previous
//
#include <hip/hip_runtime.h>

// GCN link classifier, fp32, CSR-gather aggregation, fused layers,
// pre-scaled features + unroll-4 gather (latency fix).
// Pipeline (10 dispatches):
//   memset deg; k_deg; k_scan1(+dinv); k_scan2; k_scan3; k_fill   (CSR build)
//   k_xs : xs = dinv * x                                (prescale)
//   k_l1 : agg1=di*(xs_i+Sum xs_s), h1=relu(agg1@W1+b1), xl2s=di*(h1@W2)
//   k_l2 : agg2=di*(xl2s_i+Sum xl2s_s)... h2=relu(agg2+b2), gt/gb=h2@Wm1
//   k_edge: out[e] = relu(gt[u]+gb[v]+bm1)@Wm2 + bm2

#define HIDN 32
#define SCAN_B 256

__global__ void k_deg(const int* __restrict__ dst, int E, int* __restrict__ deg) {
    int e = blockIdx.x * blockDim.x + threadIdx.x;
    if (e < E) atomicAdd(&deg[dst[e]], 1);
}

// per-block exclusive scan; bsum[b] = block total; also dinv = rsqrt(deg+1)
__global__ void k_scan1(const int* __restrict__ deg, int N,
                        int* __restrict__ part, int* __restrict__ bsum,
                        float* __restrict__ dinv) {
    __shared__ int sh[SCAN_B];
    int t = threadIdx.x, i = blockIdx.x * SCAN_B + t;
    int v = (i < N) ? deg[i] : 0;
    if (i < N) dinv[i] = rsqrtf((float)(v + 1));   // +1 = self loop
    sh[t] = v; __syncthreads();
    for (int o = 1; o < SCAN_B; o <<= 1) {
        int a = (t >= o) ? sh[t - o] : 0;
        __syncthreads();
        sh[t] += a;
        __syncthreads();
    }
    if (i < N) part[i] = sh[t] - v;          // exclusive
    if (t == SCAN_B - 1) bsum[blockIdx.x] = sh[t];
}

// single-block exclusive scan of block sums (nb <= 1024)
__global__ void k_scan2(int* __restrict__ bsum, int nb) {
    __shared__ int sh[1024];
    int t = threadIdx.x;
    int v = (t < nb) ? bsum[t] : 0;
    sh[t] = v; __syncthreads();
    for (int o = 1; o < 1024; o <<= 1) {
        int a = (t >= o) ? sh[t - o] : 0;
        __syncthreads();
        sh[t] += a;
        __syncthreads();
    }
    if (t < nb) bsum[t] = sh[t] - v;         // exclusive, in place
}

// rowptr[i] = part[i] + bsum[i/SCAN_B]; cursor = rowptr; rowptr[N] = E
__global__ void k_scan3(const int* __restrict__ part, const int* __restrict__ bsum,
                        int N, int E, int* __restrict__ rowptr, int* __restrict__ cursor) {
    int i = blockIdx.x * blockDim.x + threadIdx.x;
    if (i < N) {
        int r = part[i] + bsum[i / SCAN_B];
        rowptr[i] = r;
        cursor[i] = r;
    }
    if (i == N) rowptr[N] = E;
}

__global__ void k_fill(const int* __restrict__ src, const int* __restrict__ dst, int E,
                       int* __restrict__ cursor, int* __restrict__ csr) {
    int e = blockIdx.x * blockDim.x + threadIdx.x;
    if (e < E) {
        int j = atomicAdd(&cursor[dst[e]], 1);
        csr[j] = src[e];
    }
}

// xs = dinv[i] * x[i]   (prescale so gathers need no per-neighbor dinv load)
__global__ void k_xs(const float4* __restrict__ x, const float* __restrict__ dinv,
                     int N, float4* __restrict__ xs) {
    int t = blockIdx.x * blockDim.x + threadIdx.x;   // N*8
    if (t >= N * 8) return;
    float w = dinv[t >> 3];
    float4 a = x[t];
    a.x *= w; a.y *= w; a.z *= w; a.w *= w;
    xs[t] = a;
}

// ---- fused layer 1: agg1 = di*(xs_i + Sum_s xs_s); h1 = relu(agg1@W1+b1);
//      xl2s = di * (h1@W2)      (pre-scaled for layer-2 gather)
// block = 256 threads = 8 nodes x 32 lanes (lane j = feature j)
__global__ __launch_bounds__(256) void k_l1(
        const float* __restrict__ xs, const float* __restrict__ dinv,
        const int* __restrict__ rowptr, const int* __restrict__ csr,
        const float* __restrict__ W1, const float* __restrict__ b1,
        const float* __restrict__ W2, int N, float* __restrict__ xl2s) {
    __shared__ float ash[8][33];
    __shared__ float hsh[8][129];
    int j = threadIdx.x & 31, ln = threadIdx.x >> 5;
    int i = blockIdx.x * 8 + ln;
    float acc = 0.f, di = 0.f;
    int beg = 0, end = 0;
    if (i < N) {
        di = dinv[i];
        acc = xs[(size_t)i * 32 + j];          // self-loop term (pre-scaled)
        beg = rowptr[i]; end = rowptr[i + 1];
    }
    int p = beg;
    for (; p + 3 < end; p += 4) {              // 4 independent loads in flight
        int s0 = csr[p], s1 = csr[p + 1], s2 = csr[p + 2], s3 = csr[p + 3];
        float a0 = xs[(size_t)s0 * 32 + j];
        float a1 = xs[(size_t)s1 * 32 + j];
        float a2 = xs[(size_t)s2 * 32 + j];
        float a3 = xs[(size_t)s3 * 32 + j];
        acc += (a0 + a1) + (a2 + a3);
    }
    for (; p < end; ++p) acc += xs[(size_t)csr[p] * 32 + j];
    ash[ln][j] = acc * di;
    __syncthreads();
    if (i < N) {
        float h0 = b1[j], h1v = b1[j + 32], h2v = b1[j + 64], h3v = b1[j + 96];
#pragma unroll
        for (int k = 0; k < 32; ++k) {
            float a = ash[ln][k];                 // broadcast
            h0  = fmaf(a, W1[k * 128 + j     ], h0);
            h1v = fmaf(a, W1[k * 128 + j + 32], h1v);
            h2v = fmaf(a, W1[k * 128 + j + 64], h2v);
            h3v = fmaf(a, W1[k * 128 + j + 96], h3v);
        }
        hsh[ln][j]      = fmaxf(h0, 0.f);
        hsh[ln][j + 32] = fmaxf(h1v, 0.f);
        hsh[ln][j + 64] = fmaxf(h2v, 0.f);
        hsh[ln][j + 96] = fmaxf(h3v, 0.f);
    }
    __syncthreads();
    if (i >= N) return;
    float s2 = 0.f;
#pragma unroll 16
    for (int k = 0; k < 128; ++k) s2 = fmaf(hsh[ln][k], W2[k * 32 + j], s2);
    xl2s[(size_t)i * 32 + j] = di * s2;        // pre-scaled for layer 2
}

// ---- fused layer 2 + edge-MLP factorization:
// agg2 = di*(xl2s_i + Sum_s xl2s_s)   (note di*xl2_i == xl2s_i)
// h2 = relu(agg2+b2); gt = h2@Wm1[:32]; gb = h2@Wm1[32:]
__global__ __launch_bounds__(256) void k_l2(
        const float* __restrict__ xl2s, const float* __restrict__ dinv,
        const int* __restrict__ rowptr, const int* __restrict__ csr,
        const float* __restrict__ b2, const float* __restrict__ Wm1,
        int N, float* __restrict__ gt, float* __restrict__ gb) {
    __shared__ float hsh[8][33];
    int j = threadIdx.x & 31, ln = threadIdx.x >> 5;
    int i = blockIdx.x * 8 + ln;
    float acc = 0.f, di = 0.f;
    int beg = 0, end = 0;
    if (i < N) {
        di = dinv[i];
        acc = xl2s[(size_t)i * 32 + j];
        beg = rowptr[i]; end = rowptr[i + 1];
    }
    int p = beg;
    for (; p + 3 < end; p += 4) {
        int s0 = csr[p], s1 = csr[p + 1], s2 = csr[p + 2], s3 = csr[p + 3];
        float a0 = xl2s[(size_t)s0 * 32 + j];
        float a1 = xl2s[(size_t)s1 * 32 + j];
        float a2 = xl2s[(size_t)s2 * 32 + j];
        float a3 = xl2s[(size_t)s3 * 32 + j];
        acc += (a0 + a1) + (a2 + a3);
    }
    for (; p < end; ++p) acc += xl2s[(size_t)csr[p] * 32 + j];
    float h2 = (i < N) ? fmaxf(acc * di + b2[j], 0.f) : 0.f;
    hsh[ln][j] = h2;
    __syncthreads();
    if (i >= N) return;
    float st = 0.f, sb = 0.f;
#pragma unroll
    for (int k = 0; k < 32; ++k) {
        float a = hsh[ln][k];
        st = fmaf(a, Wm1[k * 32 + j], st);
        sb = fmaf(a, Wm1[(k + 32) * 32 + j], sb);
    }
    gt[(size_t)i * 32 + j] = st;
    gb[(size_t)i * 32 + j] = sb;
}

// out[e] = relu(gt[u] + gb[v] + bm1) @ Wm2 + bm2
__global__ void k_edge(const int* __restrict__ ps, const int* __restrict__ pd, int Ep,
                       const int* __restrict__ ns, const int* __restrict__ nd, int En,
                       const float4* __restrict__ gt4, const float4* __restrict__ gb4,
                       const float* __restrict__ bm1, const float* __restrict__ Wm2,
                       const float* __restrict__ bm2, float2* __restrict__ out) {
    int e = blockIdx.x * blockDim.x + threadIdx.x;
    int E = Ep + En;
    if (e >= E) return;
    int u, v;
    if (e < Ep) { u = ps[e]; v = pd[e]; }
    else        { u = ns[e - Ep]; v = nd[e - Ep]; }
    float o0 = bm2[0], o1 = bm2[1];
#pragma unroll
    for (int q = 0; q < 8; ++q) {
        float4 a = gt4[(size_t)u * 8 + q];
        float4 b = gb4[(size_t)v * 8 + q];
        float h;
        h = fmaxf(a.x + b.x + bm1[q * 4 + 0], 0.f);
        o0 = fmaf(h, Wm2[(q * 4 + 0) * 2 + 0], o0); o1 = fmaf(h, Wm2[(q * 4 + 0) * 2 + 1], o1);
        h = fmaxf(a.y + b.y + bm1[q * 4 + 1], 0.f);
        o0 = fmaf(h, Wm2[(q * 4 + 1) * 2 + 0], o0); o1 = fmaf(h, Wm2[(q * 4 + 1) * 2 + 1], o1);
        h = fmaxf(a.z + b.z + bm1[q * 4 + 2], 0.f);
        o0 = fmaf(h, Wm2[(q * 4 + 2) * 2 + 0], o0); o1 = fmaf(h, Wm2[(q * 4 + 2) * 2 + 1], o1);
        h = fmaxf(a.w + b.w + bm1[q * 4 + 3], 0.f);
        o0 = fmaf(h, Wm2[(q * 4 + 3) * 2 + 0], o0); o1 = fmaf(h, Wm2[(q * 4 + 3) * 2 + 1], o1);
    }
    out[e] = make_float2(o0, o1);
}

extern "C" void kernel_launch(void* const* d_in, const int* in_sizes, int n_in,
                              void* d_out, int out_size, void* d_ws, size_t ws_size,
                              hipStream_t stream) {
    const float* x   = (const float*)d_in[0];
    const int*   pei = (const int*)d_in[1];
    const int*   nei = (const int*)d_in[2];
    const float* W1  = (const float*)d_in[3];
    const float* b1  = (const float*)d_in[4];
    const float* W2  = (const float*)d_in[5];
    const float* b2  = (const float*)d_in[6];
    const float* Wm1 = (const float*)d_in[7];
    const float* bm1 = (const float*)d_in[8];
    const float* Wm2 = (const float*)d_in[9];
    const float* bm2 = (const float*)d_in[10];

    const int N  = in_sizes[0] / HIDN;
    const int Ep = in_sizes[1] / 2;
    const int En = in_sizes[2] / 2;
    const int* ps = pei;            // pos src
    const int* pd = pei + Ep;       // pos dst
    const int* ns = nei;
    const int* nd = nei + En;
    const int nb = (N + SCAN_B - 1) / SCAN_B;   // scan blocks (<= 1024)

    // workspace layout (256B-aligned slabs)
    char* ws = (char*)d_ws;
    size_t off = 0;
    auto alloc = [&](size_t bytes) { size_t o = off; off += (bytes + 255) & ~(size_t)255; return o; };
    int*   deg    = (int*)(ws + alloc((size_t)N * 4));
    float* dinv   = (float*)(ws + alloc((size_t)N * 4));
    int*   part   = (int*)(ws + alloc((size_t)N * 4));
    int*   bsum   = (int*)(ws + alloc((size_t)1024 * 4));
    int*   rowptr = (int*)(ws + alloc((size_t)(N + 1) * 4));
    int*   cursor = (int*)(ws + alloc((size_t)N * 4));
    int*   csr    = (int*)(ws + alloc((size_t)Ep * 4));
    float* xs     = (float*)(ws + alloc((size_t)N * HIDN * 4));
    float* xl2s   = (float*)(ws + alloc((size_t)N * HIDN * 4));
    float* gt     = (float*)(ws + alloc((size_t)N * HIDN * 4));
    float* gb     = (float*)(ws + alloc((size_t)N * HIDN * 4));

    // ---- CSR build (once; reused by both layers) ----
    hipMemsetAsync(deg, 0, (size_t)N * 4, stream);
    k_deg<<<(Ep + 255) / 256, 256, 0, stream>>>(pd, Ep, deg);
    k_scan1<<<nb, SCAN_B, 0, stream>>>(deg, N, part, bsum, dinv);
    k_scan2<<<1, 1024, 0, stream>>>(bsum, nb);
    k_scan3<<<(N + 256) / 256, 256, 0, stream>>>(part, bsum, N, Ep, rowptr, cursor);
    k_fill<<<(Ep + 255) / 256, 256, 0, stream>>>(ps, pd, Ep, cursor, csr);

    // ---- prescale + fused GCN layers ----
    k_xs<<<(N * 8 + 255) / 256, 256, 0, stream>>>((const float4*)x, dinv, N, (float4*)xs);
    k_l1<<<(N + 7) / 8, 256, 0, stream>>>(xs, dinv, rowptr, csr, W1, b1, W2, N, xl2s);
    k_l2<<<(N + 7) / 8, 256, 0, stream>>>(xl2s, dinv, rowptr, csr, b2, Wm1, N, gt, gb);

    // ---- edge MLP over pos+neg edges ----
    k_edge<<<(Ep + En + 255) / 256, 256, 0, stream>>>(ps, pd, Ep, ns, nd, En,
                                                      (const float4*)gt, (const float4*)gb,
                                                      bm1, Wm2, bm2, (float2*)d_out);
}

// Round 6
// 480.212 us; speedup vs baseline: 3.6262x; 1.1138x over previous
//
#include <hip/hip_runtime.h>

// GCN link classifier, fp32, CSR-gather aggregation, fused layers,
// pre-scaled features, unroll-8 gather, 8-threads-per-edge MLP (MLP = latency fix).
// Pipeline (9 dispatches):
//   memset deg; k_deg; k_scan1(+dinv+prescale); k_scan2; k_scan3; k_fill  (CSR)
//   k_l1 : agg1=di*(xs_i+Sum xs_s), h1=relu(agg1@W1+b1), xl2s=di*(h1@W2)
//   k_l2 : agg2=xl2s_i+di*Sum xl2s_s, h2=relu(agg2+b2), gt/gb=h2@Wm1
//   k_edge: out[e] = relu(gt[u]+gb[v]+bm1)@Wm2 + bm2    (8 lanes/edge)

#define HIDN 32
#define SCAN_B 256

__global__ void k_deg(const int* __restrict__ dst, int E, int* __restrict__ deg) {
    int e = blockIdx.x * blockDim.x + threadIdx.x;
    if (e < E) atomicAdd(&deg[dst[e]], 1);
}

// per-block exclusive scan; bsum[b] = block total; dinv = rsqrt(deg+1);
// also prescale xs = dinv * x for this block's 256 nodes (coalesced float4 loop).
__global__ void k_scan1(const int* __restrict__ deg, int N,
                        int* __restrict__ part, int* __restrict__ bsum,
                        float* __restrict__ dinv,
                        const float4* __restrict__ x4, float4* __restrict__ xs4) {
    __shared__ int sh[SCAN_B];
    __shared__ float dsh[SCAN_B];
    int t = threadIdx.x, i = blockIdx.x * SCAN_B + t;
    int v = (i < N) ? deg[i] : 0;
    float dv = rsqrtf((float)(v + 1));       // +1 = self loop
    if (i < N) dinv[i] = dv;
    dsh[t] = dv;
    sh[t] = v; __syncthreads();
    for (int o = 1; o < SCAN_B; o <<= 1) {
        int a = (t >= o) ? sh[t - o] : 0;
        __syncthreads();
        sh[t] += a;
        __syncthreads();
    }
    if (i < N) part[i] = sh[t] - v;          // exclusive
    if (t == SCAN_B - 1) bsum[blockIdx.x] = sh[t];
    // prescale: this block's nodes span quads [blk*2048, blk*2048+2048)
#pragma unroll
    for (int it = 0; it < 8; ++it) {
        int q = it * SCAN_B + t;             // quad within block
        int g = blockIdx.x * (SCAN_B * 8) + q;
        if (g < N * 8) {
            float w = dsh[q >> 3];
            float4 a = x4[g];
            a.x *= w; a.y *= w; a.z *= w; a.w *= w;
            xs4[g] = a;
        }
    }
}

// single-block exclusive scan of block sums (nb <= 1024)
__global__ void k_scan2(int* __restrict__ bsum, int nb) {
    __shared__ int sh[1024];
    int t = threadIdx.x;
    int v = (t < nb) ? bsum[t] : 0;
    sh[t] = v; __syncthreads();
    for (int o = 1; o < 1024; o <<= 1) {
        int a = (t >= o) ? sh[t - o] : 0;
        __syncthreads();
        sh[t] += a;
        __syncthreads();
    }
    if (t < nb) bsum[t] = sh[t] - v;         // exclusive, in place
}

// rowptr[i] = part[i] + bsum[i/SCAN_B]; cursor = rowptr; rowptr[N] = E
__global__ void k_scan3(const int* __restrict__ part, const int* __restrict__ bsum,
                        int N, int E, int* __restrict__ rowptr, int* __restrict__ cursor) {
    int i = blockIdx.x * blockDim.x + threadIdx.x;
    if (i < N) {
        int r = part[i] + bsum[i / SCAN_B];
        rowptr[i] = r;
        cursor[i] = r;
    }
    if (i == N) rowptr[N] = E;
}

__global__ void k_fill(const int* __restrict__ src, const int* __restrict__ dst, int E,
                       int* __restrict__ cursor, int* __restrict__ csr) {
    int e = blockIdx.x * blockDim.x + threadIdx.x;
    if (e < E) {
        int j = atomicAdd(&cursor[dst[e]], 1);
        csr[j] = src[e];
    }
}

// ---- fused layer 1: agg1 = di*(xs_i/di... ) — xs pre-scaled:
//      agg1 = di*(xs_i + Sum_s xs_s)  with xs_i = di*x_i handled via acc init.
// block = 256 threads = 8 nodes x 32 lanes (lane j = feature j)
__global__ __launch_bounds__(256) void k_l1(
        const float* __restrict__ xs, const float* __restrict__ dinv,
        const int* __restrict__ rowptr, const int* __restrict__ csr,
        const float* __restrict__ W1, const float* __restrict__ b1,
        const float* __restrict__ W2, int N, float* __restrict__ xl2s) {
    __shared__ float ash[8][33];
    __shared__ float hsh[8][129];
    int j = threadIdx.x & 31, ln = threadIdx.x >> 5;
    int i = blockIdx.x * 8 + ln;
    float acc = 0.f, di = 0.f;
    int beg = 0, end = 0;
    if (i < N) {
        di = dinv[i];
        acc = xs[(size_t)i * 32 + j];          // self-loop term (pre-scaled)
        beg = rowptr[i]; end = rowptr[i + 1];
    }
    int p = beg;
    for (; p + 7 < end; p += 8) {              // 8 independent loads in flight
        int s0 = csr[p],     s1 = csr[p + 1], s2 = csr[p + 2], s3 = csr[p + 3];
        int s4 = csr[p + 4], s5 = csr[p + 5], s6 = csr[p + 6], s7 = csr[p + 7];
        float a0 = xs[(size_t)s0 * 32 + j];
        float a1 = xs[(size_t)s1 * 32 + j];
        float a2 = xs[(size_t)s2 * 32 + j];
        float a3 = xs[(size_t)s3 * 32 + j];
        float a4 = xs[(size_t)s4 * 32 + j];
        float a5 = xs[(size_t)s5 * 32 + j];
        float a6 = xs[(size_t)s6 * 32 + j];
        float a7 = xs[(size_t)s7 * 32 + j];
        acc += ((a0 + a1) + (a2 + a3)) + ((a4 + a5) + (a6 + a7));
    }
    for (; p + 3 < end; p += 4) {
        int s0 = csr[p], s1 = csr[p + 1], s2 = csr[p + 2], s3 = csr[p + 3];
        float a0 = xs[(size_t)s0 * 32 + j];
        float a1 = xs[(size_t)s1 * 32 + j];
        float a2 = xs[(size_t)s2 * 32 + j];
        float a3 = xs[(size_t)s3 * 32 + j];
        acc += (a0 + a1) + (a2 + a3);
    }
    for (; p < end; ++p) acc += xs[(size_t)csr[p] * 32 + j];
    ash[ln][j] = acc * di;
    __syncthreads();
    if (i < N) {
        float h0 = b1[j], h1v = b1[j + 32], h2v = b1[j + 64], h3v = b1[j + 96];
#pragma unroll
        for (int k = 0; k < 32; ++k) {
            float a = ash[ln][k];                 // broadcast
            h0  = fmaf(a, W1[k * 128 + j     ], h0);
            h1v = fmaf(a, W1[k * 128 + j + 32], h1v);
            h2v = fmaf(a, W1[k * 128 + j + 64], h2v);
            h3v = fmaf(a, W1[k * 128 + j + 96], h3v);
        }
        hsh[ln][j]      = fmaxf(h0, 0.f);
        hsh[ln][j + 32] = fmaxf(h1v, 0.f);
        hsh[ln][j + 64] = fmaxf(h2v, 0.f);
        hsh[ln][j + 96] = fmaxf(h3v, 0.f);
    }
    __syncthreads();
    if (i >= N) return;
    float s2 = 0.f;
#pragma unroll 16
    for (int k = 0; k < 128; ++k) s2 = fmaf(hsh[ln][k], W2[k * 32 + j], s2);
    xl2s[(size_t)i * 32 + j] = di * s2;        // pre-scaled for layer 2
}

// ---- fused layer 2 + edge-MLP factorization:
// agg2 = di*(xl2s_i + Sum_s xl2s_s)   (di*xl2_i == xl2s_i)
// h2 = relu(agg2+b2); gt = h2@Wm1[:32]; gb = h2@Wm1[32:]
__global__ __launch_bounds__(256) void k_l2(
        const float* __restrict__ xl2s, const float* __restrict__ dinv,
        const int* __restrict__ rowptr, const int* __restrict__ csr,
        const float* __restrict__ b2, const float* __restrict__ Wm1,
        int N, float* __restrict__ gt, float* __restrict__ gb) {
    __shared__ float hsh[8][33];
    int j = threadIdx.x & 31, ln = threadIdx.x >> 5;
    int i = blockIdx.x * 8 + ln;
    float acc = 0.f, di = 0.f;
    int beg = 0, end = 0;
    if (i < N) {
        di = dinv[i];
        acc = xl2s[(size_t)i * 32 + j];
        beg = rowptr[i]; end = rowptr[i + 1];
    }
    int p = beg;
    for (; p + 7 < end; p += 8) {
        int s0 = csr[p],     s1 = csr[p + 1], s2 = csr[p + 2], s3 = csr[p + 3];
        int s4 = csr[p + 4], s5 = csr[p + 5], s6 = csr[p + 6], s7 = csr[p + 7];
        float a0 = xl2s[(size_t)s0 * 32 + j];
        float a1 = xl2s[(size_t)s1 * 32 + j];
        float a2 = xl2s[(size_t)s2 * 32 + j];
        float a3 = xl2s[(size_t)s3 * 32 + j];
        float a4 = xl2s[(size_t)s4 * 32 + j];
        float a5 = xl2s[(size_t)s5 * 32 + j];
        float a6 = xl2s[(size_t)s6 * 32 + j];
        float a7 = xl2s[(size_t)s7 * 32 + j];
        acc += ((a0 + a1) + (a2 + a3)) + ((a4 + a5) + (a6 + a7));
    }
    for (; p + 3 < end; p += 4) {
        int s0 = csr[p], s1 = csr[p + 1], s2 = csr[p + 2], s3 = csr[p + 3];
        float a0 = xl2s[(size_t)s0 * 32 + j];
        float a1 = xl2s[(size_t)s1 * 32 + j];
        float a2 = xl2s[(size_t)s2 * 32 + j];
        float a3 = xl2s[(size_t)s3 * 32 + j];
        acc += (a0 + a1) + (a2 + a3);
    }
    for (; p < end; ++p) acc += xl2s[(size_t)csr[p] * 32 + j];
    float h2 = (i < N) ? fmaxf(acc * di + b2[j], 0.f) : 0.f;
    hsh[ln][j] = h2;
    __syncthreads();
    if (i >= N) return;
    float st = 0.f, sb = 0.f;
#pragma unroll
    for (int k = 0; k < 32; ++k) {
        float a = hsh[ln][k];
        st = fmaf(a, Wm1[k * 32 + j], st);
        sb = fmaf(a, Wm1[(k + 32) * 32 + j], sb);
    }
    gt[(size_t)i * 32 + j] = st;
    gb[(size_t)i * 32 + j] = sb;
}

// out[e] = relu(gt[u] + gb[v] + bm1) @ Wm2 + bm2
// 8 lanes per edge: lane q loads float4 q of gt[u] and gb[v], computes 4 hidden
// units, 8-lane shuffle-reduce produces the float2 output.
__global__ void k_edge(const int* __restrict__ ps, const int* __restrict__ pd, int Ep,
                       const int* __restrict__ ns, const int* __restrict__ nd, int En,
                       const float4* __restrict__ gt4, const float4* __restrict__ gb4,
                       const float* __restrict__ bm1, const float* __restrict__ Wm2,
                       const float* __restrict__ bm2, float2* __restrict__ out) {
    int t = blockIdx.x * blockDim.x + threadIdx.x;   // E*8 threads
    int e = t >> 3, q = t & 7;
    int E = Ep + En;
    if (e >= E) return;
    int u, v;
    if (e < Ep) { u = ps[e]; v = pd[e]; }
    else        { u = ns[e - Ep]; v = nd[e - Ep]; }
    float4 a = gt4[(size_t)u * 8 + q];
    float4 b = gb4[(size_t)v * 8 + q];
    int k0 = q * 4;
    float o0 = 0.f, o1 = 0.f, h;
    h = fmaxf(a.x + b.x + bm1[k0 + 0], 0.f);
    o0 = fmaf(h, Wm2[(k0 + 0) * 2 + 0], o0); o1 = fmaf(h, Wm2[(k0 + 0) * 2 + 1], o1);
    h = fmaxf(a.y + b.y + bm1[k0 + 1], 0.f);
    o0 = fmaf(h, Wm2[(k0 + 1) * 2 + 0], o0); o1 = fmaf(h, Wm2[(k0 + 1) * 2 + 1], o1);
    h = fmaxf(a.z + b.z + bm1[k0 + 2], 0.f);
    o0 = fmaf(h, Wm2[(k0 + 2) * 2 + 0], o0); o1 = fmaf(h, Wm2[(k0 + 2) * 2 + 1], o1);
    h = fmaxf(a.w + b.w + bm1[k0 + 3], 0.f);
    o0 = fmaf(h, Wm2[(k0 + 3) * 2 + 0], o0); o1 = fmaf(h, Wm2[(k0 + 3) * 2 + 1], o1);
    o0 += __shfl_down(o0, 4, 8); o1 += __shfl_down(o1, 4, 8);
    o0 += __shfl_down(o0, 2, 8); o1 += __shfl_down(o1, 2, 8);
    o0 += __shfl_down(o0, 1, 8); o1 += __shfl_down(o1, 1, 8);
    if (q == 0) out[e] = make_float2(o0 + bm2[0], o1 + bm2[1]);
}

extern "C" void kernel_launch(void* const* d_in, const int* in_sizes, int n_in,
                              void* d_out, int out_size, void* d_ws, size_t ws_size,
                              hipStream_t stream) {
    const float* x   = (const float*)d_in[0];
    const int*   pei = (const int*)d_in[1];
    const int*   nei = (const int*)d_in[2];
    const float* W1  = (const float*)d_in[3];
    const float* b1  = (const float*)d_in[4];
    const float* W2  = (const float*)d_in[5];
    const float* b2  = (const float*)d_in[6];
    const float* Wm1 = (const float*)d_in[7];
    const float* bm1 = (const float*)d_in[8];
    const float* Wm2 = (const float*)d_in[9];
    const float* bm2 = (const float*)d_in[10];

    const int N  = in_sizes[0] / HIDN;
    const int Ep = in_sizes[1] / 2;
    const int En = in_sizes[2] / 2;
    const int* ps = pei;            // pos src
    const int* pd = pei + Ep;       // pos dst
    const int* ns = nei;
    const int* nd = nei + En;
    const int nb = (N + SCAN_B - 1) / SCAN_B;   // scan blocks (<= 1024)

    // workspace layout (256B-aligned slabs)
    char* ws = (char*)d_ws;
    size_t off = 0;
    auto alloc = [&](size_t bytes) { size_t o = off; off += (bytes + 255) & ~(size_t)255; return o; };
    int*   deg    = (int*)(ws + alloc((size_t)N * 4));
    float* dinv   = (float*)(ws + alloc((size_t)N * 4));
    int*   part   = (int*)(ws + alloc((size_t)N * 4));
    int*   bsum   = (int*)(ws + alloc((size_t)1024 * 4));
    int*   rowptr = (int*)(ws + alloc((size_t)(N + 1) * 4));
    int*   cursor = (int*)(ws + alloc((size_t)N * 4));
    int*   csr    = (int*)(ws + alloc((size_t)Ep * 4));
    float* xs     = (float*)(ws + alloc((size_t)N * HIDN * 4));
    float* xl2s   = (float*)(ws + alloc((size_t)N * HIDN * 4));
    float* gt     = (float*)(ws + alloc((size_t)N * HIDN * 4));
    float* gb     = (float*)(ws + alloc((size_t)N * HIDN * 4));

    // ---- CSR build (once; reused by both layers) + prescale ----
    hipMemsetAsync(deg, 0, (size_t)N * 4, stream);
    k_deg<<<(Ep + 255) / 256, 256, 0, stream>>>(pd, Ep, deg);
    k_scan1<<<nb, SCAN_B, 0, stream>>>(deg, N, part, bsum, dinv,
                                       (const float4*)x, (float4*)xs);
    k_scan2<<<1, 1024, 0, stream>>>(bsum, nb);
    k_scan3<<<(N + 256) / 256, 256, 0, stream>>>(part, bsum, N, Ep, rowptr, cursor);
    k_fill<<<(Ep + 255) / 256, 256, 0, stream>>>(ps, pd, Ep, cursor, csr);

    // ---- fused GCN layers ----
    k_l1<<<(N + 7) / 8, 256, 0, stream>>>(xs, dinv, rowptr, csr, W1, b1, W2, N, xl2s);
    k_l2<<<(N + 7) / 8, 256, 0, stream>>>(xl2s, dinv, rowptr, csr, b2, Wm1, N, gt, gb);

    // ---- edge MLP over pos+neg edges (8 lanes/edge) ----
    {
        size_t threads = (size_t)(Ep + En) * 8;
        k_edge<<<(int)((threads + 255) / 256), 256, 0, stream>>>(
            ps, pd, Ep, ns, nd, En,
            (const float4*)gt, (const float4*)gb,
            bm1, Wm2, bm2, (float2*)d_out);
    }
}